// Round 15
// baseline (158.709 us; speedup 1.0000x reference)
//
#include <hip/hip_runtime.h>
#include <hip/hip_cooperative_groups.h>
#include <math.h>

namespace cg = cooperative_groups;

#define B_N 4096
#define C_N 100
#define D_N 384
#define EPSF 1e-12f
#define CT 5           // classes per tile
#define NT 20          // class tiles
#define NK (D_N / 16)  // 24 k-steps of 16 dims
#define KW (NK / 4)    // 6 k-steps per wave
#define RT 64          // rows per block (4 rows per thread)
#define NRT (B_N / RT) // 64 input rowtiles; rowtiles 64,65 are center rows
#define NWI (NT * (NRT + 2))   // 1320 work items

// tbl layout, CLASS-major (float4 units):
//   tbl4[(c*NK + k)*8 + seg]     = m2wc = -2 * w2 * center
//   tbl4[(c*NK + k)*8 + seg + 4] = w2
// d2(x, class c) = a2[c] + sum_d ( (w2*x + m2wc) * x )

__global__ __launch_bounds__(256, 2) void k_all(const float* __restrict__ inputs,
                                                const float* __restrict__ centers,
                                                const float* __restrict__ cw,
                                                const int* __restrict__ targets,
                                                float* __restrict__ tbl,
                                                float* __restrict__ a2,
                                                int* __restrict__ present,
                                                int* __restrict__ apmax,
                                                int* __restrict__ anmin,
                                                float* __restrict__ cdmin,
                                                float* __restrict__ out) {
    __shared__ __align__(16) float4 tb[CT * NK * 8];   // 15360 B (aliased in epilogue)
    __shared__ float sred[4];
    __shared__ int ps[4];
    __shared__ float cd_s[C_N];
    __shared__ float sw[4];

    cg::grid_group gg = cg::this_grid();
    int tid = threadIdx.x;
    int bid = blockIdx.x;
    int w    = tid >> 6;
    int l    = tid & 63;
    int slot = l & 15;
    int seg  = l >> 4;

    // ================= phase 1: prep =================
    if (bid < C_N) {
        int c = bid;
        float acc = 0.f;
        for (int d = tid; d < D_N; d += 256) {
            float wv = exp2f(cw[c * D_N + d]);
            float ce = centers[c * D_N + d];
            float p  = wv * ce;
            int k = d >> 4, sg = (d >> 2) & 3, e = d & 3;
            int base = ((c * NK + k) * 8 + sg) * 4 + e;
            tbl[base]      = -2.f * p;   // m2wc
            tbl[base + 16] = wv;         // w2
            acc = fmaf(p, ce, acc);
        }
        for (int m = 1; m < 64; m <<= 1) acc += __shfl_xor(acc, m, 64);

        int pr = 0;
        for (int i = tid; i < B_N; i += 256) pr |= (targets[i] == c) ? 1 : 0;
        pr = __any(pr) ? 1 : 0;

        if (l == 0) { sred[w] = acc; ps[w] = pr; }
        __syncthreads();
        if (tid == 0) {
            a2[c] = (sred[0] + sred[1]) + (sred[2] + sred[3]);
            present[c] = ps[0] | ps[1] | ps[2] | ps[3];
        }
    } else if (bid < C_N + 16) {
        int idx = (bid - C_N) * 256 + tid;   // covers 4096 rows
        apmax[idx] = 0;                      // all g > 0
        anmin[idx] = 0x7F800000;             // +inf
    }
    gg.sync();

    // ================= phase 2: main (grid-stride over 1320 tiles) =================
    for (int wi = bid; wi < NWI; wi += gridDim.x) {
        __syncthreads();   // guard: previous item's gbuf readers vs new staging writes
        int ctile   = wi % NT;
        int rowtile = wi / NT;
        int c0 = ctile * CT;
        bool isc = (rowtile >= NRT);

        const float *xp0, *xp1, *xp2, *xp3;
        if (!isc) {
            const float* base = inputs + (size_t)(rowtile * RT + slot) * D_N + seg * 4;
            xp0 = base;
            xp1 = base + 16 * D_N;
            xp2 = base + 32 * D_N;
            xp3 = base + 48 * D_N;
        } else {
            int cb = (rowtile - NRT) * RT + slot;
            int r0 = min(cb,      C_N - 1);
            int r1 = min(cb + 16, C_N - 1);
            int r2 = min(cb + 32, C_N - 1);
            int r3 = min(cb + 48, C_N - 1);
            xp0 = centers + (size_t)r0 * D_N + seg * 4;
            xp1 = centers + (size_t)r1 * D_N + seg * 4;
            xp2 = centers + (size_t)r2 * D_N + seg * 4;
            xp3 = centers + (size_t)r3 * D_N + seg * 4;
        }

        int k0 = w * KW;
        float4 xr0 = *(const float4*)(xp0 + k0 * 16);
        float4 xr1 = *(const float4*)(xp1 + k0 * 16);
        float4 xr2 = *(const float4*)(xp2 + k0 * 16);
        float4 xr3 = *(const float4*)(xp3 + k0 * 16);

        {
            const float4* gsrc = (const float4*)tbl + (size_t)c0 * NK * 8;
            for (int q = tid; q < CT * NK * 8; q += 256) tb[q] = gsrc[q];
        }
        __syncthreads();

        float u[4][CT];
#pragma unroll
        for (int rr = 0; rr < 4; rr++)
#pragma unroll
            for (int j = 0; j < CT; j++) u[rr][j] = 0.f;

#pragma unroll 1
        for (int kk = 0; kk < KW; kk++) {
            int k = w * KW + kk;
            int kn = (kk + 1 < KW) ? (k + 1) : k;
            float4 xn0 = *(const float4*)(xp0 + kn * 16);
            float4 xn1 = *(const float4*)(xp1 + kn * 16);
            float4 xn2 = *(const float4*)(xp2 + kn * 16);
            float4 xn3 = *(const float4*)(xp3 + kn * 16);

            const float4* tk = tb + k * 8 + seg;
#pragma unroll
            for (int j = 0; j < CT; j++) {
                float4 m2 = tk[j * (NK * 8)];       // -2*w2*c
                float4 wv = tk[j * (NK * 8) + 4];   // w2
                float t;
                t = fmaf(wv.x, xr0.x, m2.x); u[0][j] = fmaf(t, xr0.x, u[0][j]);
                t = fmaf(wv.y, xr0.y, m2.y); u[0][j] = fmaf(t, xr0.y, u[0][j]);
                t = fmaf(wv.z, xr0.z, m2.z); u[0][j] = fmaf(t, xr0.z, u[0][j]);
                t = fmaf(wv.w, xr0.w, m2.w); u[0][j] = fmaf(t, xr0.w, u[0][j]);
                t = fmaf(wv.x, xr1.x, m2.x); u[1][j] = fmaf(t, xr1.x, u[1][j]);
                t = fmaf(wv.y, xr1.y, m2.y); u[1][j] = fmaf(t, xr1.y, u[1][j]);
                t = fmaf(wv.z, xr1.z, m2.z); u[1][j] = fmaf(t, xr1.z, u[1][j]);
                t = fmaf(wv.w, xr1.w, m2.w); u[1][j] = fmaf(t, xr1.w, u[1][j]);
                t = fmaf(wv.x, xr2.x, m2.x); u[2][j] = fmaf(t, xr2.x, u[2][j]);
                t = fmaf(wv.y, xr2.y, m2.y); u[2][j] = fmaf(t, xr2.y, u[2][j]);
                t = fmaf(wv.z, xr2.z, m2.z); u[2][j] = fmaf(t, xr2.z, u[2][j]);
                t = fmaf(wv.w, xr2.w, m2.w); u[2][j] = fmaf(t, xr2.w, u[2][j]);
                t = fmaf(wv.x, xr3.x, m2.x); u[3][j] = fmaf(t, xr3.x, u[3][j]);
                t = fmaf(wv.y, xr3.y, m2.y); u[3][j] = fmaf(t, xr3.y, u[3][j]);
                t = fmaf(wv.z, xr3.z, m2.z); u[3][j] = fmaf(t, xr3.z, u[3][j]);
                t = fmaf(wv.w, xr3.w, m2.w); u[3][j] = fmaf(t, xr3.w, u[3][j]);
            }
            xr0 = xn0; xr1 = xn1; xr2 = xn2; xr3 = xn3;
        }

#pragma unroll
        for (int rr = 0; rr < 4; rr++)
#pragma unroll
            for (int j = 0; j < CT; j++) {
                float a = u[rr][j];
                a += __shfl_xor(a, 16, 64);
                a += __shfl_xor(a, 32, 64);
                u[rr][j] = a;
            }

        __syncthreads();   // all waves done reading tb
        float4* red4 = (float4*)tb;
        float*  gbuf = (float*)tb + 4 * CT * RT;
        if (l < 16) {
#pragma unroll
            for (int j = 0; j < CT; j++)
                red4[(w * CT + j) * 16 + slot] =
                    make_float4(u[0][j], u[1][j], u[2][j], u[3][j]);
        }
        __syncthreads();

        const float* red = (const float*)red4;
#pragma unroll
        for (int part = 0; part < 2; part++) {
            int p = tid + part * 256;
            if (p < CT * RT) {
                int j = p >> 6, r = p & 63;
                int rr = r >> 4, sl = r & 15;
                int idx = (j * 16 + sl) * 4 + rr;
                float s = (red[(0 * CT * 16) * 4 + idx] + red[(1 * CT * 16) * 4 + idx])
                        + (red[(2 * CT * 16) * 4 + idx] + red[(3 * CT * 16) * 4 + idx]);
                gbuf[j * RT + r] = sqrtf(fmaxf(a2[c0 + j] + s, EPSF));
            }
        }
        __syncthreads();

        if (!isc) {
            if (tid < RT) {
                int row = rowtile * RT + tid;
                int ti  = targets[row];
                float ap = -1.f, an = INFINITY;
#pragma unroll
                for (int j = 0; j < CT; j++) {
                    int c = c0 + j;
                    float g = gbuf[j * RT + tid];
                    if (c == ti) ap = g;
                    else if (present[c]) an = fminf(an, g);
                }
                if (ap > 0.f) atomicMax(&apmax[row], __float_as_int(ap));
                atomicMin(&anmin[row], __float_as_int(an));
            }
        } else {
            int jj = tid >> 4, sl = tid & 15;
            int rbase = (rowtile - NRT) * RT;
            if (jj < CT) {
                float m = INFINITY;
#pragma unroll
                for (int q = 0; q < 4; q++) {
                    int r  = sl + 16 * q;
                    int jg = rbase + r;
                    float g = gbuf[jj * RT + r];
                    if (jg < C_N && jg != c0 + jj) m = fminf(m, g);
                }
                m = fminf(m, __shfl_xor(m, 1, 64));
                m = fminf(m, __shfl_xor(m, 2, 64));
                m = fminf(m, __shfl_xor(m, 4, 64));
                m = fminf(m, __shfl_xor(m, 8, 64));
                if (sl == 0) cdmin[(c0 + jj) * 2 + (rbase >> 6)] = m;
            }
        }
    }
    gg.sync();

    // ================= phase 3: final (block 0) =================
    if (bid == 0) {
        if (tid < C_N) cd_s[tid] = fminf(cdmin[tid * 2], cdmin[tid * 2 + 1]);
        __syncthreads();

        float sum = 0.f;
        for (int row = tid; row < B_N; row += 256) {
            float ap = __int_as_float(apmax[row]);
            float an = __int_as_float(anmin[row]);
            float cc = cd_s[targets[row]];
            sum += (an >= cc) ? ap : (ap - an + cc);
        }
        for (int m = 1; m < 64; m <<= 1) sum += __shfl_xor(sum, m, 64);
        if (l == 0) sw[w] = sum;
        __syncthreads();
        if (tid == 0) out[0] = ((sw[0] + sw[1]) + (sw[2] + sw[3])) / (float)B_N;
    }
}

extern "C" void kernel_launch(void* const* d_in, const int* in_sizes, int n_in,
                              void* d_out, int out_size, void* d_ws, size_t ws_size,
                              hipStream_t stream) {
    const float* inputs  = (const float*)d_in[0];
    const float* centers = (const float*)d_in[1];
    const float* cw      = (const float*)d_in[2];
    const int*   targets = (const int*)d_in[3];
    (void)in_sizes; (void)n_in; (void)out_size; (void)ws_size;

    char* ws = (char*)d_ws;
    float* tbl     = (float*)(ws + 0);         // 307200 B
    int*   apmax   = (int*)  (ws + 307200);    // 16384 B
    int*   anmin   = (int*)  (ws + 323584);    // 16384 B
    float* a2      = (float*)(ws + 339968);    // 512 B
    int*   present = (int*)  (ws + 340480);    // 512 B
    float* cdmin   = (float*)(ws + 340992);    // 800 B
    float* outp    = (float*)d_out;

    // co-residency sizing for grid sync (grid-stride keeps work deterministic
    // for any grid size)
    int nb = 0;
    hipOccupancyMaxActiveBlocksPerMultiprocessor(&nb, k_all, 256, 0);
    if (nb < 1) nb = 1;
    long long cap = (long long)nb * 256;       // 256 CUs on MI355X
    int gridsz = (int)((cap < NWI) ? cap : NWI);

    void* args[] = {(void*)&inputs, (void*)&centers, (void*)&cw, (void*)&targets,
                    (void*)&tbl, (void*)&a2, (void*)&present, (void*)&apmax,
                    (void*)&anmin, (void*)&cdmin, (void*)&outp};
    hipLaunchCooperativeKernel((void*)k_all, dim3(gridsz), dim3(256), args, 0, stream);
}

// Round 16
// 41.450 us; speedup vs baseline: 3.8289x; 3.8289x over previous
//
#include <hip/hip_runtime.h>
#include <math.h>

#define B_N 4096
#define C_N 100
#define D_N 384
#define EPSF 1e-12f
#define CT 5           // classes per tile
#define NT 20          // class tiles
#define NK (D_N / 16)  // 24 k-steps of 16 dims
#define KW (NK / 4)    // 6 k-steps per wave
#define RT 64          // rows per block (4 rows per thread)
#define NRT (B_N / RT) // 64 input rowtiles; rowtiles 64,65 are center rows

// Self-contained k_main: each block builds its own 5-class table slice in LDS
// from centers/cw (no k_prep, no global tbl round-trip).
//   tb[(j*NK + k)*8 + seg]     = m2wc = -2 * w2 * center   (float4, dims k*16+seg*4..+3)
//   tb[(j*NK + k)*8 + seg + 4] = w2
// d2(x, class c0+j) = a2_s[j] + sum_d ( (w2*x + m2wc) * x )
// rowtile < NRT: x = input rows -> per-row ap/an into apan[ctile].
// rowtile >= NRT: x = center rows (clamped pad) -> cdist partial mins into cdmin.
__global__ __launch_bounds__(256) void k_main(const float* __restrict__ inputs,
                                              const float* __restrict__ centers,
                                              const float* __restrict__ cw,
                                              const int* __restrict__ targets,
                                              float2* __restrict__ apan,
                                              float* __restrict__ cdmin) {
    __shared__ __align__(16) float4 tb[CT * NK * 8];   // 15360 B (aliased in epilogue)
    __shared__ float a2_s[CT];
    __shared__ int ps[4];

    int tid  = threadIdx.x;
    int w    = tid >> 6;
    int l    = tid & 63;
    int slot = l & 15;
    int seg  = l >> 4;
    int ctile   = blockIdx.x;
    int rowtile = blockIdx.y;
    int c0 = ctile * CT;
    bool isc = (rowtile >= NRT);

    // ---- per-thread row pointers (4 rows: slot + 16*rr)
    const float *xp0, *xp1, *xp2, *xp3;
    if (!isc) {
        const float* base = inputs + (size_t)(rowtile * RT + slot) * D_N + seg * 4;
        xp0 = base;
        xp1 = base + 16 * D_N;
        xp2 = base + 32 * D_N;
        xp3 = base + 48 * D_N;
    } else {
        int cb = (rowtile - NRT) * RT + slot;
        int r0 = min(cb,      C_N - 1);
        int r1 = min(cb + 16, C_N - 1);
        int r2 = min(cb + 32, C_N - 1);
        int r3 = min(cb + 48, C_N - 1);
        xp0 = centers + (size_t)r0 * D_N + seg * 4;
        xp1 = centers + (size_t)r1 * D_N + seg * 4;
        xp2 = centers + (size_t)r2 * D_N + seg * 4;
        xp3 = centers + (size_t)r3 * D_N + seg * 4;
    }

    // issue kk=0 x prefetch first (overlaps the build phase)
    int k0 = w * KW;
    float4 xr0 = *(const float4*)(xp0 + k0 * 16);
    float4 xr1 = *(const float4*)(xp1 + k0 * 16);
    float4 xr2 = *(const float4*)(xp2 + k0 * 16);
    float4 xr3 = *(const float4*)(xp3 + k0 * 16);

    // ---- build table slice + a2 in LDS: wave w -> class w; wave 0 also class 4.
    // Deterministic (fixed wave->class map, shuffle reduce; no float atomics).
    for (int pass = 0; pass < 2; pass++) {
        if (pass == 1 && w != 0) break;
        int j = pass ? 4 : w;
        const float4* cwj = (const float4*)(cw      + (size_t)(c0 + j) * D_N);
        const float4* cej = (const float4*)(centers + (size_t)(c0 + j) * D_N);
        float pd = 0.f;
        for (int dq = l; dq < 96; dq += 64) {        // dims 4*dq .. 4*dq+3
            float4 c4 = cwj[dq], e4 = cej[dq];
            float4 wv;
            wv.x = exp2f(c4.x); wv.y = exp2f(c4.y);
            wv.z = exp2f(c4.z); wv.w = exp2f(c4.w);
            float px = wv.x * e4.x, py = wv.y * e4.y;
            float pz = wv.z * e4.z, pw = wv.w * e4.w;
            int k = dq >> 2, sg = dq & 3;            // k = d>>4, sg = (d>>2)&3
            tb[(j * NK + k) * 8 + sg]     = make_float4(-2.f * px, -2.f * py,
                                                        -2.f * pz, -2.f * pw);
            tb[(j * NK + k) * 8 + sg + 4] = wv;
            pd = fmaf(px, e4.x, pd);
            pd = fmaf(py, e4.y, pd);
            pd = fmaf(pz, e4.z, pd);
            pd = fmaf(pw, e4.w, pd);
        }
        for (int m = 1; m < 64; m <<= 1) pd += __shfl_xor(pd, m, 64);
        if (l == 0) a2_s[j] = pd;
    }

    // ---- present mask for this ctile (5 bits), coalesced targets scan
    {
        int pr = 0;
        if (!isc) {
            for (int i = tid; i < B_N; i += 256) {
                int dj = targets[i] - c0;
                if (0 <= dj && dj < CT) pr |= 1 << dj;
            }
        }
        for (int m = 1; m < 64; m <<= 1) pr |= __shfl_xor(pr, m, 64);
        if (l == 0) ps[w] = pr;
    }
    __syncthreads();

    float u[4][CT];
#pragma unroll
    for (int rr = 0; rr < 4; rr++)
#pragma unroll
        for (int j = 0; j < CT; j++) u[rr][j] = 0.f;

#pragma unroll 1
    for (int kk = 0; kk < KW; kk++) {
        int k = w * KW + kk;
        int kn = (kk + 1 < KW) ? (k + 1) : k;
        float4 xn0 = *(const float4*)(xp0 + kn * 16);
        float4 xn1 = *(const float4*)(xp1 + kn * 16);
        float4 xn2 = *(const float4*)(xp2 + kn * 16);
        float4 xn3 = *(const float4*)(xp3 + kn * 16);

        const float4* tk = tb + k * 8 + seg;
#pragma unroll
        for (int j = 0; j < CT; j++) {
            float4 m2 = tk[j * (NK * 8)];       // -2*w2*c
            float4 wv = tk[j * (NK * 8) + 4];   // w2
            float t;
            t = fmaf(wv.x, xr0.x, m2.x); u[0][j] = fmaf(t, xr0.x, u[0][j]);
            t = fmaf(wv.y, xr0.y, m2.y); u[0][j] = fmaf(t, xr0.y, u[0][j]);
            t = fmaf(wv.z, xr0.z, m2.z); u[0][j] = fmaf(t, xr0.z, u[0][j]);
            t = fmaf(wv.w, xr0.w, m2.w); u[0][j] = fmaf(t, xr0.w, u[0][j]);
            t = fmaf(wv.x, xr1.x, m2.x); u[1][j] = fmaf(t, xr1.x, u[1][j]);
            t = fmaf(wv.y, xr1.y, m2.y); u[1][j] = fmaf(t, xr1.y, u[1][j]);
            t = fmaf(wv.z, xr1.z, m2.z); u[1][j] = fmaf(t, xr1.z, u[1][j]);
            t = fmaf(wv.w, xr1.w, m2.w); u[1][j] = fmaf(t, xr1.w, u[1][j]);
            t = fmaf(wv.x, xr2.x, m2.x); u[2][j] = fmaf(t, xr2.x, u[2][j]);
            t = fmaf(wv.y, xr2.y, m2.y); u[2][j] = fmaf(t, xr2.y, u[2][j]);
            t = fmaf(wv.z, xr2.z, m2.z); u[2][j] = fmaf(t, xr2.z, u[2][j]);
            t = fmaf(wv.w, xr2.w, m2.w); u[2][j] = fmaf(t, xr2.w, u[2][j]);
            t = fmaf(wv.x, xr3.x, m2.x); u[3][j] = fmaf(t, xr3.x, u[3][j]);
            t = fmaf(wv.y, xr3.y, m2.y); u[3][j] = fmaf(t, xr3.y, u[3][j]);
            t = fmaf(wv.z, xr3.z, m2.z); u[3][j] = fmaf(t, xr3.z, u[3][j]);
            t = fmaf(wv.w, xr3.w, m2.w); u[3][j] = fmaf(t, xr3.w, u[3][j]);
        }
        xr0 = xn0; xr1 = xn1; xr2 = xn2; xr3 = xn3;
    }

    // ---- seg-reduce within wave (16-lane groups share (slot,rr))
#pragma unroll
    for (int rr = 0; rr < 4; rr++)
#pragma unroll
        for (int j = 0; j < CT; j++) {
            float a = u[rr][j];
            a += __shfl_xor(a, 16, 64);
            a += __shfl_xor(a, 32, 64);
            u[rr][j] = a;
        }

    // ---- cross-wave reduce: alias dead table LDS
    __syncthreads();   // all waves done reading tb
    float4* red4 = (float4*)tb;                     // [4w][CT][16slot] float4 (4 rr)
    float*  gbuf = (float*)tb + 4 * CT * RT;        // [CT][RT] floats
    if (l < 16) {
#pragma unroll
        for (int j = 0; j < CT; j++)
            red4[(w * CT + j) * 16 + slot] =
                make_float4(u[0][j], u[1][j], u[2][j], u[3][j]);
    }
    __syncthreads();

    // combine 4 wave-partials -> g for 320 (class,row) pairs
    const float* red = (const float*)red4;
#pragma unroll
    for (int part = 0; part < 2; part++) {
        int p = tid + part * 256;
        if (p < CT * RT) {
            int j = p >> 6, r = p & 63;
            int rr = r >> 4, sl = r & 15;
            int idx = (j * 16 + sl) * 4 + rr;
            float s = (red[(0 * CT * 16) * 4 + idx] + red[(1 * CT * 16) * 4 + idx])
                    + (red[(2 * CT * 16) * 4 + idx] + red[(3 * CT * 16) * 4 + idx]);
            gbuf[j * RT + r] = sqrtf(fmaxf(a2_s[j] + s, EPSF));
        }
    }
    __syncthreads();

    if (!isc) {
        // per-row ap/an over this ctile's classes -> apan plane (always written,
        // no init needed, deterministic)
        if (tid < RT) {
            int row = rowtile * RT + tid;
            int ti  = targets[row];
            int present = ps[0] | ps[1] | ps[2] | ps[3];
            float ap = -INFINITY, an = INFINITY;
#pragma unroll
            for (int j = 0; j < CT; j++) {
                int c = c0 + j;
                float g = gbuf[j * RT + tid];
                if (c == ti) ap = g;
                else if ((present >> j) & 1) an = fminf(an, g);
            }
            apan[(size_t)ctile * B_N + row] = make_float2(ap, an);
        }
    } else {
        // centers_dist partial: per class i = c0+jj, min over this block's center
        // rows (exclude j == i and pad rows). 16-thread group per class.
        int jj = tid >> 4, sl = tid & 15;
        int rbase = (rowtile - NRT) * RT;     // 0 or 64
        if (jj < CT) {
            float m = INFINITY;
#pragma unroll
            for (int q = 0; q < 4; q++) {
                int r  = sl + 16 * q;
                int jg = rbase + r;
                float g = gbuf[jj * RT + r];
                if (jg < C_N && jg != c0 + jj) m = fminf(m, g);
            }
            m = fminf(m, __shfl_xor(m, 1, 64));
            m = fminf(m, __shfl_xor(m, 2, 64));
            m = fminf(m, __shfl_xor(m, 4, 64));
            m = fminf(m, __shfl_xor(m, 8, 64));
            if (sl == 0) cdmin[(c0 + jj) * 2 + (rbase >> 6)] = m;
        }
    }
}

// ---------------- final: fold cdmin -> cdist, combine 20 class tiles, loss, sum
__global__ __launch_bounds__(1024) void k_final(const float2* __restrict__ apan,
                                                const float* __restrict__ cdmin,
                                                const int* __restrict__ targets,
                                                float* __restrict__ out) {
    int tid = threadIdx.x;
    __shared__ float cd_s[C_N];
    if (tid < C_N) cd_s[tid] = fminf(cdmin[tid * 2], cdmin[tid * 2 + 1]);
    __syncthreads();

    float sum = 0.f;
    for (int row = tid; row < B_N; row += 1024) {
        float ap = -INFINITY, an = INFINITY;
#pragma unroll
        for (int t = 0; t < NT; t++) {
            float2 v = apan[(size_t)t * B_N + row];
            ap = fmaxf(ap, v.x);
            an = fminf(an, v.y);
        }
        float cc = cd_s[targets[row]];
        sum += (an >= cc) ? ap : (ap - an + cc);
    }
    for (int m = 1; m < 64; m <<= 1) sum += __shfl_xor(sum, m, 64);
    __shared__ float sw[16];
    if ((tid & 63) == 0) sw[tid >> 6] = sum;
    __syncthreads();
    if (tid < 64) {
        float v = (tid < 16) ? sw[tid] : 0.f;
        for (int m = 1; m < 16; m <<= 1) v += __shfl_xor(v, m, 64);
        if (tid == 0) out[0] = v / (float)B_N;
    }
}

extern "C" void kernel_launch(void* const* d_in, const int* in_sizes, int n_in,
                              void* d_out, int out_size, void* d_ws, size_t ws_size,
                              hipStream_t stream) {
    const float* inputs  = (const float*)d_in[0];
    const float* centers = (const float*)d_in[1];
    const float* cw      = (const float*)d_in[2];
    const int*   targets = (const int*)d_in[3];
    (void)in_sizes; (void)n_in; (void)out_size; (void)ws_size;

    char* ws = (char*)d_ws;
    float2* apan  = (float2*)(ws + 0);        // 20*4096*8 = 655360 B
    float*  cdmin = (float*)(ws + 655360);    // 100*2*4

    dim3 grid(NT, NRT + 2);   // 20 x 66 = 1320 blocks
    k_main<<<grid, 256, 0, stream>>>(inputs, centers, cw, targets, apan, cdmin);
    k_final<<<1, 1024, 0, stream>>>(apan, cdmin, targets, (float*)d_out);
}